// Round 7
// baseline (623.329 us; speedup 1.0000x reference)
//
#include <hip/hip_runtime.h>

// GCN 2-layer collapsed (x is [N,1] => layer 1 is rank-1):
//   out[c] = dis[c]*(sum_{r->c} gp[r] + gp[c]) + b2,  gp[r] = (relu(W1*a[r]+b1)@W2)*dis[r]
//   a[r]   = dis[r]*(sum_{r'->r} p[r'] + p[r]),       p[r']=x[r']*dis[r'], dis=1/sqrt(deg+1)
//
// History: R1 global atomics 3.1ms -> R2 LDS-atomic buckets 478us -> R3/R4 sort-based
// partition 429us -> R5/R6: the gather+LDS-atomic aggregation pass is pinned at 175us
// REGARDLESS of occupancy (17/53/29%) and locality sort => LLC gather-line bandwidth
// floor (16M x 128B = 2GB) + LDS-atomic floor (~55us/pass).
// R7: exact CSR + segment reduce. Level A sort by col>>10 (489 chunks); level B exact
// counting sort by col&1023 per (chunk,slice); level-B hist = node degrees (deg pass
// deleted, colstart CSR from per-chunk scan). Aggregation = per-node register segment
// reduce: no LDS, no atomics, 100% occupancy; gathers hit L2-resident p(2MB)/gp(4MB).

#define KMAX 512
#define PTPB  512
#define PU    16
#define PTILE (PTPB * PU)

#define CSH   10
#define CN    1024
#define NSL   4
#define BTPB  256
#define BTILE 8192

#define ATPB  256   // path1 aggregation block

// ---------- zero ----------
__global__ void k_zero(int* __restrict__ a, int m) {
    int i = blockIdx.x * blockDim.x + threadIdx.x;
    if (i < m) a[i] = 0;
}

// ---------- coarse histogram ----------
template<int S>
__global__ void k_count(const int* __restrict__ col, int ne, int ne4,
                        int* __restrict__ totals, int K) {
    __shared__ int cnt[KMAX];
    for (int i = threadIdx.x; i < K; i += blockDim.x) cnt[i] = 0;
    __syncthreads();
    int tid = blockIdx.x * blockDim.x + threadIdx.x;
    int stride = gridDim.x * blockDim.x;
    const int4* col4 = (const int4*)col;
    for (int e = tid; e < ne4; e += stride) {
        int4 cc = col4[e];
        atomicAdd(&cnt[cc.x >> S], 1);
        atomicAdd(&cnt[cc.y >> S], 1);
        atomicAdd(&cnt[cc.z >> S], 1);
        atomicAdd(&cnt[cc.w >> S], 1);
    }
    for (int e = (ne4 << 2) + tid; e < ne; e += stride)
        atomicAdd(&cnt[col[e] >> S], 1);
    __syncthreads();
    for (int i = threadIdx.x; i < K; i += blockDim.x)
        if (cnt[i]) atomicAdd(&totals[i], cnt[i]);
}

// ---------- serial scan (K<=512) ----------
__global__ void k_scan(const int* __restrict__ totals, int* __restrict__ bbase,
                       int* __restrict__ cursor, int K) {
    if (threadIdx.x == 0 && blockIdx.x == 0) {
        int run = 0;
        for (int k = 0; k < K; ++k) { bbase[k] = run; cursor[k] = run; run += totals[k]; }
        bbase[K] = run;
    }
}

// ---------- tile-local LDS counting sort partition (key = col>>S) ----------
template<int S>
__global__ __launch_bounds__(PTPB) void k_part(
    const int* __restrict__ row, const int* __restrict__ col, int ne,
    int* __restrict__ cursor, int* __restrict__ packed, int K)
{
    constexpr int CNL = 1 << S;
    __shared__ int s_cnt[KMAX];
    __shared__ int s_start[KMAX + 1];
    __shared__ int s_cur[KMAX];
    __shared__ int s_gbase[KMAX];
    __shared__ int s_sorted[PTILE];

    int tb = blockIdx.x * PTILE;
    int tilecount = ne - tb;
    if (tilecount > PTILE) tilecount = PTILE;

    for (int i = threadIdx.x; i < K; i += PTPB) s_cnt[i] = 0;
    __syncthreads();

    int r[PU], c[PU];
    const int4* row4 = (const int4*)row;
    const int4* col4 = (const int4*)col;
    int tb4 = tb >> 2;
#pragma unroll
    for (int j = 0; j < PU / 4; ++j) {
        int g4 = tb4 + j * PTPB + threadIdx.x;
        int e = g4 << 2;
        if (e + 3 < ne) {
            int4 rr = row4[g4];
            int4 cc = col4[g4];
            r[4 * j + 0] = rr.x; r[4 * j + 1] = rr.y; r[4 * j + 2] = rr.z; r[4 * j + 3] = rr.w;
            c[4 * j + 0] = cc.x; c[4 * j + 1] = cc.y; c[4 * j + 2] = cc.z; c[4 * j + 3] = cc.w;
        } else {
#pragma unroll
            for (int q = 0; q < 4; ++q) {
                int e2 = e + q;
                if (e2 < ne) { r[4 * j + q] = row[e2]; c[4 * j + q] = col[e2]; }
                else { r[4 * j + q] = 0; c[4 * j + q] = -1; }
            }
        }
    }
#pragma unroll
    for (int j = 0; j < PU; ++j)
        if (c[j] >= 0) atomicAdd(&s_cnt[c[j] >> S], 1);
    __syncthreads();

    if (threadIdx.x == 0) {
        int run = 0;
        for (int k = 0; k < K; ++k) { s_start[k] = run; run += s_cnt[k]; }
        s_start[K] = run;
    }
    __syncthreads();
    if ((int)threadIdx.x < K) {
        int n0 = s_cnt[threadIdx.x];
        s_gbase[threadIdx.x] = n0 ? atomicAdd(&cursor[threadIdx.x], n0) : 0;
        s_cur[threadIdx.x] = s_start[threadIdx.x];
    }
    __syncthreads();

#pragma unroll
    for (int j = 0; j < PU; ++j) {
        if (c[j] >= 0) {
            int ck = c[j] >> S;
            int pos = atomicAdd(&s_cur[ck], 1);
            s_sorted[pos] = (r[j] << S) | (c[j] & (CNL - 1));
        }
    }
    __syncthreads();

    for (int i = threadIdx.x; i < tilecount; i += PTPB) {
        int v = s_sorted[i];
        int lo = 0, hi = K;
        while (hi - lo > 1) {
            int mid = (lo + hi) >> 1;
            if (s_start[mid] <= i) lo = mid; else hi = mid;
        }
        packed[s_gbase[lo] + (i - s_start[lo])] = v;
    }
}

// ---------- path2: per (chunk,slice) node-level histogram -> pcnt (ushort) ----------
__global__ __launch_bounds__(BTPB) void k_hist(
    const int* __restrict__ packedA, const int* __restrict__ cbase,
    unsigned short* __restrict__ pcnt, int n)
{
    __shared__ int cnt[CN];
    int k = blockIdx.x / NSL, sl = blockIdx.x % NSL;
    int node0 = k << CSH;
    int nn = min(CN, n - node0);
    for (int i = threadIdx.x; i < CN; i += BTPB) cnt[i] = 0;
    __syncthreads();
    int e0 = cbase[k], e1 = cbase[k + 1];
    long long len = e1 - e0;
    int es = e0 + (int)((len * sl) / NSL);
    int ee = e0 + (int)((len * (sl + 1)) / NSL);
    int a0 = min((es + 3) & ~3, ee);
    int a1 = max(ee & ~3, a0);
    for (int e = es + (int)threadIdx.x; e < a0; e += BTPB)
        atomicAdd(&cnt[packedA[e] & (CN - 1)], 1);
    const int4* p4 = (const int4*)packedA;
    for (int i4 = (a0 >> 2) + (int)threadIdx.x; i4 < (a1 >> 2); i4 += BTPB) {
        int4 v = p4[i4];
        atomicAdd(&cnt[v.x & (CN - 1)], 1);
        atomicAdd(&cnt[v.y & (CN - 1)], 1);
        atomicAdd(&cnt[v.z & (CN - 1)], 1);
        atomicAdd(&cnt[v.w & (CN - 1)], 1);
    }
    for (int e = a1 + (int)threadIdx.x; e < ee; e += BTPB)
        atomicAdd(&cnt[packedA[e] & (CN - 1)], 1);
    __syncthreads();
    unsigned short* dst = pcnt + (size_t)sl * n + node0;
    for (int i = threadIdx.x; i < nn; i += BTPB) dst[i] = (unsigned short)cnt[i];
}

// ---------- path2: per-chunk scan -> colstart CSR + dis + p (deg pass folded in) ----------
__global__ __launch_bounds__(BTPB) void k_csr(
    const float* __restrict__ x, const unsigned short* __restrict__ pcnt,
    const int* __restrict__ cbase, int* __restrict__ colstart,
    float* __restrict__ dis, float* __restrict__ p, int n, int chunks)
{
    __shared__ int ps[BTPB];
    int k = blockIdx.x;
    int node0 = k << CSH;
    int nn = min(CN, n - node0);
    int t = threadIdx.x;
    int d[4];
    int mysum = 0;
#pragma unroll
    for (int j = 0; j < 4; ++j) {
        int idx = t * 4 + j;
        int dv = 0;
        if (idx < nn) {
#pragma unroll
            for (int sl = 0; sl < NSL; ++sl)
                dv += pcnt[(size_t)sl * n + node0 + idx];
        }
        d[j] = dv; mysum += dv;
    }
    ps[t] = mysum;
    __syncthreads();
    for (int off = 1; off < BTPB; off <<= 1) {
        int v = (t >= off) ? ps[t - off] : 0;
        __syncthreads();
        ps[t] += v;
        __syncthreads();
    }
    int base = cbase[k] + ((t == 0) ? 0 : ps[t - 1]);
#pragma unroll
    for (int j = 0; j < 4; ++j) {
        int idx = t * 4 + j;
        if (idx < nn) {
            colstart[node0 + idx] = base;
            float ds = rsqrtf(1.0f + (float)d[j]);
            dis[node0 + idx] = ds;
            p[node0 + idx] = x[node0 + idx] * ds;
            base += d[j];
        }
    }
    if (k == chunks - 1 && t == 0) colstart[n] = cbase[chunks];
}

// ---------- path2: exact placement (deterministic, no global atomics) ----------
__global__ __launch_bounds__(BTPB) void k_place(
    const int* __restrict__ packedA, const int* __restrict__ cbase,
    const unsigned short* __restrict__ pcnt, const int* __restrict__ colstart,
    int* __restrict__ packedB, int n)
{
    __shared__ int cur[CN];
    __shared__ int cnt[CN];
    __shared__ int start[CN + 1];
    __shared__ int ps[BTPB];
    __shared__ int sorted[BTILE];

    int k = blockIdx.x / NSL, sl = blockIdx.x % NSL;
    int node0 = k << CSH;
    int nn = min(CN, n - node0);

    for (int i = threadIdx.x; i < nn; i += BTPB) {
        int c = colstart[node0 + i];
        for (int t = 0; t < sl; ++t) c += pcnt[(size_t)t * n + node0 + i];
        cur[i] = c;
    }

    int e0 = cbase[k], e1 = cbase[k + 1];
    long long len = e1 - e0;
    int es = e0 + (int)((len * sl) / NSL);
    int ee = e0 + (int)((len * (sl + 1)) / NSL);

    for (int t0 = es; t0 < ee; t0 += BTILE) {
        int tc = min(BTILE, ee - t0);
        __syncthreads();
        for (int i = threadIdx.x; i < CN; i += BTPB) cnt[i] = 0;
        __syncthreads();
        for (int j = threadIdx.x; j < tc; j += BTPB)
            atomicAdd(&cnt[packedA[t0 + j] & (CN - 1)], 1);
        __syncthreads();
        int t = threadIdx.x;
        int b4 = t * 4;
        int l0 = cnt[b4], l1 = cnt[b4 + 1], l2 = cnt[b4 + 2], l3 = cnt[b4 + 3];
        ps[t] = l0 + l1 + l2 + l3;
        __syncthreads();
        for (int off = 1; off < BTPB; off <<= 1) {
            int v = (t >= off) ? ps[t - off] : 0;
            __syncthreads();
            ps[t] += v;
            __syncthreads();
        }
        int b = (t == 0) ? 0 : ps[t - 1];
        start[b4] = b; start[b4 + 1] = b + l0; start[b4 + 2] = b + l0 + l1;
        start[b4 + 3] = b + l0 + l1 + l2;
        if (t == 0) start[CN] = tc;
        __syncthreads();
        for (int i = threadIdx.x; i < CN; i += BTPB) cnt[i] = start[i];
        __syncthreads();
        for (int j = threadIdx.x; j < tc; j += BTPB) {
            int v = packedA[t0 + j];
            int pos = atomicAdd(&cnt[v & (CN - 1)], 1);
            sorted[pos] = v;
        }
        __syncthreads();
        for (int i = threadIdx.x; i < tc; i += BTPB) {
            int v = sorted[i];
            int key = v & (CN - 1);
            packedB[cur[key] + (i - start[key])] = (int)(((unsigned)v) >> CSH);
        }
        __syncthreads();
        for (int i = threadIdx.x; i < CN; i += BTPB) cur[i] += cnt[i] - start[i];
    }
}

// ---------- path2: segment reduce s + fused MLP -> gp ----------
__global__ __launch_bounds__(256) void k_sgp_seg(
    const int* __restrict__ packedB, const int* __restrict__ colstart,
    const float* __restrict__ p, const float* __restrict__ dis,
    const float* __restrict__ W1, const float* __restrict__ b1,
    const float* __restrict__ W2, float* __restrict__ gp, int n)
{
    int i = blockIdx.x * 256 + threadIdx.x;
    if (i >= n) return;
    int e0 = colstart[i], e1 = colstart[i + 1];
    float s0 = p[i], s1 = 0.f, s2 = 0.f, s3 = 0.f;
    int e = e0;
    for (; e + 3 < e1; e += 4) {
        int r0 = packedB[e], r1 = packedB[e + 1], r2 = packedB[e + 2], r3 = packedB[e + 3];
        s0 += p[r0]; s1 += p[r1]; s2 += p[r2]; s3 += p[r3];
    }
    for (; e < e1; ++e) s0 += p[packedB[e]];
    float d = dis[i];
    float a = d * (s0 + s1 + s2 + s3);
    float g0 = 0.f, g1 = 0.f;
#pragma unroll
    for (int q = 0; q < 16; ++q) {
        float h = fmaxf(W1[q] * a + b1[q], 0.0f);
        g0 += h * W2[2 * q];
        g1 += h * W2[2 * q + 1];
    }
    ((float2*)gp)[i] = make_float2(g0 * d, g1 * d);
}

// ---------- path2: segment reduce -> out ----------
__global__ __launch_bounds__(256) void k_out_seg(
    const int* __restrict__ packedB, const int* __restrict__ colstart,
    const float* __restrict__ gp, const float* __restrict__ dis,
    const float* __restrict__ b2, float* __restrict__ out, int n)
{
    int i = blockIdx.x * 256 + threadIdx.x;
    if (i >= n) return;
    int e0 = colstart[i], e1 = colstart[i + 1];
    const float2* gp2 = (const float2*)gp;
    float2 g = gp2[i];
    float x0 = g.x, y0 = g.y, x1 = 0.f, y1 = 0.f;
    int e = e0;
    for (; e + 1 < e1; e += 2) {
        float2 a = gp2[packedB[e]];
        float2 b = gp2[packedB[e + 1]];
        x0 += a.x; y0 += a.y;
        x1 += b.x; y1 += b.y;
    }
    if (e < e1) { float2 a = gp2[packedB[e]]; x0 += a.x; y0 += a.y; }
    float d = dis[i];
    ((float2*)out)[i] = make_float2(d * (x0 + x1) + b2[0], d * (y0 + y1) + b2[1]);
}

// ---------- path1 (R5) helpers ----------
template<int S>
__device__ inline void slice_bounds(const int* bbase, int k, int s, int& es, int& ee) {
    int e0 = bbase[k], e1 = bbase[k + 1];
    long long len = e1 - e0;
    es = e0 + (int)((len * s) / S);
    ee = e0 + (int)((len * (s + 1)) / S);
}

template<int S2, int S>
__global__ __launch_bounds__(ATPB) void k_deg_split(
    const int* __restrict__ packed, const int* __restrict__ bbase,
    int* __restrict__ pcnt, int n)
{
    constexpr int CNL = 1 << S2;
    __shared__ int cnt[CNL];
    int k = blockIdx.x / S, s = blockIdx.x % S;
    int node0 = k << S2;
    int nn = min(CNL, n - node0);
    for (int i = threadIdx.x; i < nn; i += ATPB) cnt[i] = 0;
    __syncthreads();
    int es, ee;
    slice_bounds<S>(bbase, k, s, es, ee);
    for (int e = es + (int)threadIdx.x; e < ee; e += ATPB)
        atomicAdd(&cnt[packed[e] & (CNL - 1)], 1);
    __syncthreads();
    int* dst = pcnt + (size_t)s * n + node0;
    for (int i = threadIdx.x; i < nn; i += ATPB) dst[i] = cnt[i];
}

template<int S>
__global__ void r_dis_p(const float* __restrict__ x, const int* __restrict__ pcnt,
                        float* __restrict__ dis, float* __restrict__ p, int n)
{
    int i = blockIdx.x * blockDim.x + threadIdx.x;
    if (i >= n) return;
    int d = 1;
#pragma unroll
    for (int s = 0; s < S; ++s) d += pcnt[(size_t)s * n + i];
    float ds = rsqrtf((float)d);
    dis[i] = ds;
    p[i] = x[i] * ds;
}

template<int S2, int S>
__global__ __launch_bounds__(ATPB) void k_s_split(
    const int* __restrict__ packed, const int* __restrict__ bbase,
    const float* __restrict__ p, float* __restrict__ ps, int n)
{
    constexpr int CNL = 1 << S2;
    __shared__ float sv[CNL];
    int k = blockIdx.x / S, s = blockIdx.x % S;
    int node0 = k << S2;
    int nn = min(CNL, n - node0);
    for (int i = threadIdx.x; i < nn; i += ATPB) sv[i] = 0.0f;
    __syncthreads();
    int es, ee;
    slice_bounds<S>(bbase, k, s, es, ee);
    for (int e = es + (int)threadIdx.x; e < ee; e += ATPB) {
        int v = packed[e];
        atomicAdd(&sv[v & (CNL - 1)], p[((unsigned)v) >> S2]);
    }
    __syncthreads();
    float* dst = ps + (size_t)s * n + node0;
    for (int i = threadIdx.x; i < nn; i += ATPB) dst[i] = sv[i];
}

template<int S>
__global__ void r_gp(const float* __restrict__ ps, const float* __restrict__ p,
                     const float* __restrict__ dis,
                     const float* __restrict__ W1, const float* __restrict__ b1,
                     const float* __restrict__ W2, float* __restrict__ gp, int n)
{
    int i = blockIdx.x * blockDim.x + threadIdx.x;
    if (i >= n) return;
    float sum = p[i];
#pragma unroll
    for (int s = 0; s < S; ++s) sum += ps[(size_t)s * n + i];
    float d = dis[i];
    float a = d * sum;
    float g0 = 0.0f, g1 = 0.0f;
#pragma unroll
    for (int q = 0; q < 16; ++q) {
        float h = fmaxf(W1[q] * a + b1[q], 0.0f);
        g0 += h * W2[2 * q];
        g1 += h * W2[2 * q + 1];
    }
    ((float2*)gp)[i] = make_float2(g0 * d, g1 * d);
}

template<int S2, int S>
__global__ __launch_bounds__(ATPB) void k_o_split(
    const int* __restrict__ packed, const int* __restrict__ bbase,
    const float* __restrict__ gp, float* __restrict__ pout, int n)
{
    constexpr int CNL = 1 << S2;
    __shared__ float ox[CNL];
    __shared__ float oy[CNL];
    int k = blockIdx.x / S, s = blockIdx.x % S;
    int node0 = k << S2;
    int nn = min(CNL, n - node0);
    for (int i = threadIdx.x; i < nn; i += ATPB) { ox[i] = 0.0f; oy[i] = 0.0f; }
    __syncthreads();
    int es, ee;
    slice_bounds<S>(bbase, k, s, es, ee);
    const float2* gp2 = (const float2*)gp;
    for (int e = es + (int)threadIdx.x; e < ee; e += ATPB) {
        int v = packed[e];
        float2 g = gp2[((unsigned)v) >> S2];
        atomicAdd(&ox[v & (CNL - 1)], g.x);
        atomicAdd(&oy[v & (CNL - 1)], g.y);
    }
    __syncthreads();
    float2* dst = (float2*)pout + (size_t)s * n + node0;
    for (int i = threadIdx.x; i < nn; i += ATPB) dst[i] = make_float2(ox[i], oy[i]);
}

template<int S>
__global__ void r_out(const float* __restrict__ pout, const float* __restrict__ gp,
                      const float* __restrict__ dis, const float* __restrict__ b2,
                      float* __restrict__ out, int n)
{
    int i = blockIdx.x * blockDim.x + threadIdx.x;
    if (i >= n) return;
    const float2* po2 = (const float2*)pout;
    float2 g = ((const float2*)gp)[i];
    float sx = g.x, sy = g.y;
#pragma unroll
    for (int s = 0; s < S; ++s) {
        float2 t = po2[(size_t)s * n + i];
        sx += t.x; sy += t.y;
    }
    float d = dis[i];
    ((float2*)out)[i] = make_float2(d * sx + b2[0], d * sy + b2[1]);
}

// ---------- R1 fallback ----------
__global__ void f_init_deg(float* __restrict__ deg, int n) {
    int i = blockIdx.x * blockDim.x + threadIdx.x;
    if (i < n) deg[i] = 1.0f;
}
__global__ void f_deg(const int* __restrict__ col, float* __restrict__ deg, int ne) {
    int tid = blockIdx.x * blockDim.x + threadIdx.x;
    int stride = gridDim.x * blockDim.x;
    for (int e = tid; e < ne; e += stride) atomicAdd(&deg[col[e]], 1.0f);
}
__global__ void f_dis(const float* __restrict__ x, float* __restrict__ deg_dis,
                      float* __restrict__ p, float* __restrict__ s, int n) {
    int i = blockIdx.x * blockDim.x + threadIdx.x;
    if (i >= n) return;
    float dis = rsqrtf(deg_dis[i]);
    deg_dis[i] = dis;
    float pv = x[i] * dis;
    p[i] = pv;
    s[i] = pv;
}
__global__ void f_scatter1(const int* __restrict__ row, const int* __restrict__ col,
                           const float* __restrict__ p, float* __restrict__ s, int ne) {
    int tid = blockIdx.x * blockDim.x + threadIdx.x;
    int stride = gridDim.x * blockDim.x;
    for (int e = tid; e < ne; e += stride) atomicAdd(&s[col[e]], p[row[e]]);
}
__global__ void f_node(const float* __restrict__ dis, const float* __restrict__ s,
                       const float* __restrict__ W1, const float* __restrict__ b1,
                       const float* __restrict__ W2,
                       float* __restrict__ gp, float* __restrict__ out, int n) {
    int i = blockIdx.x * blockDim.x + threadIdx.x;
    if (i >= n) return;
    float d = dis[i];
    float a = d * s[i];
    float g0 = 0.0f, g1 = 0.0f;
#pragma unroll
    for (int q = 0; q < 16; ++q) {
        float h = fmaxf(W1[q] * a + b1[q], 0.0f);
        g0 += h * W2[2 * q];
        g1 += h * W2[2 * q + 1];
    }
    ((float2*)gp)[i] = make_float2(g0 * d, g1 * d);
    ((float2*)out)[i] = make_float2(g0 * d, g1 * d);
}
__global__ void f_scatter2(const int* __restrict__ row, const int* __restrict__ col,
                           const float* __restrict__ gp, float* __restrict__ out, int ne) {
    int tid = blockIdx.x * blockDim.x + threadIdx.x;
    int stride = gridDim.x * blockDim.x;
    const float2* gp2 = (const float2*)gp;
    for (int e = tid; e < ne; e += stride) {
        float2 g = gp2[row[e]];
        atomicAdd(&out[2 * col[e]], g.x);
        atomicAdd(&out[2 * col[e] + 1], g.y);
    }
}
__global__ void f_final(const float* __restrict__ dis, const float* __restrict__ b2,
                        float* __restrict__ out, int n) {
    int i = blockIdx.x * blockDim.x + threadIdx.x;
    if (i >= n) return;
    float d = dis[i];
    float2* out2 = (float2*)out;
    float2 t = out2[i];
    out2[i] = make_float2(d * t.x + b2[0], d * t.y + b2[1]);
}

// ---------------- launch ----------------

extern "C" void kernel_launch(void* const* d_in, const int* in_sizes, int n_in,
                              void* d_out, int out_size, void* d_ws, size_t ws_size,
                              hipStream_t stream) {
    const float* x = (const float*)d_in[0];
    const int* edge_index = (const int*)d_in[1];
    const float* W1 = (const float*)d_in[2];
    const float* b1 = (const float*)d_in[3];
    const float* W2 = (const float*)d_in[4];
    const float* b2 = (const float*)d_in[5];
    float* out = (float*)d_out;

    int n = in_sizes[0];
    int ne = in_sizes[1] / 2;
    const int* row = edge_index;
    const int* col = edge_index + ne;

    int ne4 = ((ne & 3) == 0) ? (ne >> 2) : 0;
    int nodeBlocks = (n + 255) / 256;

    // ---------- path2: exact CSR + segment reduce ----------
    {
        int chunks = (n + CN - 1) >> CSH;
        size_t off = 0;
        auto alloc = [&](size_t bytes) -> char* {
            char* ptr = (char*)d_ws + off;
            off += (bytes + 255) & ~(size_t)255;
            return ptr;
        };
        int* totals   = (int*)alloc((size_t)chunks * sizeof(int));
        int* cbase    = (int*)alloc((size_t)(chunks + 1) * sizeof(int));
        int* cursorA  = (int*)alloc((size_t)chunks * sizeof(int));
        int* packedA  = (int*)alloc((size_t)ne * sizeof(int));
        int* packedB  = (int*)alloc((size_t)ne * sizeof(int));
        unsigned short* pcnt = (unsigned short*)alloc((size_t)NSL * n * sizeof(unsigned short));
        int* colstart = (int*)alloc((size_t)(n + 1) * sizeof(int));
        float* dis    = (float*)alloc((size_t)n * sizeof(float));
        float* p      = (float*)alloc((size_t)n * sizeof(float));
        // gp aliases packedA (dead after k_place) when it fits
        float* gp;
        if ((size_t)2 * n * sizeof(float) <= (size_t)ne * sizeof(int)) gp = (float*)packedA;
        else gp = (float*)alloc((size_t)n * 2 * sizeof(float));

        bool ok = (off <= ws_size) && (chunks >= 1) && (chunks <= KMAX) &&
                  (chunks <= PTPB) && (ne > 0) && (n >= 1);
        if (ok) {
            int partBlocks = (ne + PTILE - 1) / PTILE;
            k_zero<<<(chunks + 255) / 256, 256, 0, stream>>>(totals, chunks);
            k_count<CSH><<<1024, 256, 0, stream>>>(col, ne, ne4, totals, chunks);
            k_scan<<<1, 64, 0, stream>>>(totals, cbase, cursorA, chunks);
            k_part<CSH><<<partBlocks, PTPB, 0, stream>>>(row, col, ne, cursorA, packedA, chunks);
            k_hist<<<chunks * NSL, BTPB, 0, stream>>>(packedA, cbase, pcnt, n);
            k_csr<<<chunks, BTPB, 0, stream>>>(x, pcnt, cbase, colstart, dis, p, n, chunks);
            k_place<<<chunks * NSL, BTPB, 0, stream>>>(packedA, cbase, pcnt, colstart, packedB, n);
            k_sgp_seg<<<nodeBlocks, 256, 0, stream>>>(packedB, colstart, p, dis, W1, b1, W2, gp, n);
            k_out_seg<<<nodeBlocks, 256, 0, stream>>>(packedB, colstart, gp, dis, b2, out, n);
            return;
        }
    }

    // ---------- path1 (R5 structure) ----------
    {
        int K = (n + 1023) >> 10;
        size_t off = 0;
        auto alloc = [&](size_t bytes) -> char* {
            char* ptr = (char*)d_ws + off;
            off += (bytes + 255) & ~(size_t)255;
            return ptr;
        };
        int* totals = (int*)alloc((size_t)K * sizeof(int));
        int* bbase  = (int*)alloc((size_t)(K + 1) * sizeof(int));
        int* cursor = (int*)alloc((size_t)K * sizeof(int));
        int* packed = (int*)alloc((size_t)ne * sizeof(int));
        float* dis  = (float*)alloc((size_t)n * sizeof(float));
        float* p    = (float*)alloc((size_t)n * sizeof(float));
        float* gp   = (float*)alloc((size_t)n * 2 * sizeof(float));
        float* partials = (float*)alloc((size_t)4 * n * 2 * sizeof(float));

        bool ok = (off <= ws_size) && (K >= 1) && (K <= KMAX) && (ne > 0);
        if (ok) {
            int partBlocks = (ne + PTILE - 1) / PTILE;
            k_zero<<<(K + 255) / 256, 256, 0, stream>>>(totals, K);
            k_count<10><<<1024, 256, 0, stream>>>(col, ne, ne4, totals, K);
            k_scan<<<1, 64, 0, stream>>>(totals, bbase, cursor, K);
            k_part<10><<<partBlocks, PTPB, 0, stream>>>(row, col, ne, cursor, packed, K);
            k_deg_split<10, 4><<<K * 4, ATPB, 0, stream>>>(packed, bbase, (int*)partials, n);
            r_dis_p<4><<<nodeBlocks, 256, 0, stream>>>(x, (const int*)partials, dis, p, n);
            k_s_split<10, 4><<<K * 4, ATPB, 0, stream>>>(packed, bbase, p, partials, n);
            r_gp<4><<<nodeBlocks, 256, 0, stream>>>(partials, p, dis, W1, b1, W2, gp, n);
            k_o_split<10, 4><<<K * 4, ATPB, 0, stream>>>(packed, bbase, gp, partials, n);
            r_out<4><<<nodeBlocks, 256, 0, stream>>>(partials, gp, dis, b2, out, n);
            return;
        }
    }

    // ---------- R1 fallback ----------
    {
        float* ws = (float*)d_ws;
        float* deg_dis = ws;
        float* pp = ws + n;
        float* ss = ws + 2 * (size_t)n;
        float* gpp = ws + 3 * (size_t)n;
        int edgeBlocks = 4096;
        f_init_deg<<<nodeBlocks, 256, 0, stream>>>(deg_dis, n);
        f_deg<<<edgeBlocks, 256, 0, stream>>>(col, deg_dis, ne);
        f_dis<<<nodeBlocks, 256, 0, stream>>>(x, deg_dis, pp, ss, n);
        f_scatter1<<<edgeBlocks, 256, 0, stream>>>(row, col, pp, ss, ne);
        f_node<<<nodeBlocks, 256, 0, stream>>>(deg_dis, ss, W1, b1, W2, gpp, out, n);
        f_scatter2<<<edgeBlocks, 256, 0, stream>>>(row, col, gpp, out, ne);
        f_final<<<nodeBlocks, 256, 0, stream>>>(deg_dis, b2, out, n);
    }
}